// Round 2
// baseline (176.068 us; speedup 1.0000x reference)
//
#include <hip/hip_runtime.h>
#include <math.h>

// B=4, T=48, W=8, H=8, C=32; d_ff=64; periods {2,3,4}. T%P==0 always.
// (1x1 + 3^4)/2 inception folded into one 81-tap conv (center tap 40).
// R16 = R15 + conv1/conv2 FUSED into one kernel:
//   grid 576 = (per,bb,tp,h); block does conv1(per,bb,tp,nh=h) then waits on
//   a 24-block group barrier (per,bb,h) — exactly the producer set of the h1
//   half it consumes — then conv2(per,bb,tp,kh=h). Removes one device-wide
//   drain+launch boundary and globalizes nothing: stragglers only stall
//   their own (per,bb,h) group. Barrier counters live in ws, zeroed by prep;
//   release/acquire __threadfence around agent-scope atomics handles
//   cross-XCD L2 non-coherence. Deadlock-safe: 52 KB LDS +
//   __launch_bounds__(256,3) => 3 blk/CU => capacity 768 >= 576 co-resident.

typedef __attribute__((ext_vector_type(8))) short bf16x8;
typedef __attribute__((ext_vector_type(4))) float f32x4;
typedef unsigned short u16;

// ---- workspace offsets (u16 units) ----
#define XC 3200                 // u16 per x cell (10*10*32)
#define HC2 7168                // u16 per h1 cell (2 halves x 3584, padded)
#define XSEG 617600             // 193 * XC   (cell 192 = zero cell)
#define ZSEG_END 639104         // + 3*7168 h1 zero-cell writes
#define W1OFF 639104            // 165888 bf16: [tap 0..80][nh(2)][1024]
#define W2OFF 804992            // 165888 bf16: [tap 0..80][kh(2)][1024]
#define H1OFF 970880            // 3 periods x 193 cells x 7168
#define H1P 1383424             // per-period stride = 193*7168
#define PREP_N 970880           // end of weight segment
#define OUT_Q 98304             // out-init float4 count (393216 fp32)
#define PREP_TOT (PREP_N + OUT_Q)
#define BAROFF 5121152          // u16 offset of 24 u32 barrier counters

#define WAITVM(N) asm volatile("s_waitcnt vmcnt(" #N ")" ::: "memory")
#define SBAR()    asm volatile("s_barrier" ::: "memory")

__device__ __forceinline__ u16 f2bf(float f) {
    unsigned u = __float_as_uint(f);
    unsigned r = u + 0x7fffu + ((u >> 16) & 1u);
    return (u16)(r >> 16);
}
__device__ __forceinline__ float gelu_exact(float v) {
    return 0.5f * v * (1.0f + erff(v * 0.7071067811865476f));
}

// async copy of 1 KB: 64 lanes x 16 B. LDS dest = wave-uniform base + lane*16.
__device__ __forceinline__ void cp1k(const u16* g, u16* l, int lane) {
    __builtin_amdgcn_global_load_lds(
        (const __attribute__((address_space(1))) unsigned int*)(g + lane * 8),
        (__attribute__((address_space(3))) unsigned int*)(l + lane * 8),
        16, 0, 0);
}

// 24-block producer-group barrier. Entry __syncthreads drains each wave's
// stores (vmcnt0); thread0 release-fences (L2 writeback), arrives, spins on
// an RMW (always served at the coherent point), then acquire-fences
// (L1/L2 invalidate) so the whole block reads fresh h1 afterwards.
__device__ __forceinline__ void group_barrier(unsigned* ctr, unsigned target) {
    __syncthreads();
    if (threadIdx.x == 0) {
        __threadfence();   // release: publish this XCD's h1 lines
        __hip_atomic_fetch_add(ctr, 1u, __ATOMIC_RELEASE,
                               __HIP_MEMORY_SCOPE_AGENT);
        while (__hip_atomic_fetch_add(ctr, 0u, __ATOMIC_RELAXED,
                                      __HIP_MEMORY_SCOPE_AGENT) < target)
            __builtin_amdgcn_s_sleep(8);
        __threadfence();   // acquire: invalidate stale L1/L2 before reads
    }
    __syncthreads();
}

// ---- prep: x cells (swizzled) + h1 zero cells + weights + out = x ----
__global__ __launch_bounds__(256) void prep(
    const float* __restrict__ x,
    const float* __restrict__ w1_0, const float* __restrict__ w1_1,
    const float* __restrict__ w2_0, const float* __restrict__ w2_1,
    u16* __restrict__ ws, float* __restrict__ out) {
    int i = blockIdx.x * 256 + threadIdx.x;
    if (i < 24) ((unsigned*)(ws + BAROFF))[i] = 0;   // group-barrier counters
    if (i < XSEG) {
        int cellidx = i / XC; int inner = i - cellidx * XC;
        int cellpos = inner >> 5; int low = inner & 31;
        int sc = low >> 3, jj = low & 7;
        int c = ((sc ^ (cellpos & 3)) << 3) + jj;
        int wp = cellpos / 10, hp = cellpos - (cellpos / 10) * 10;
        float v = 0.f;
        if (cellidx < 192 && wp >= 1 && wp <= 8 && hp >= 1 && hp <= 8)
            v = x[(cellidx * 64 + (wp - 1) * 8 + (hp - 1)) * 32 + c];
        ws[i] = f2bf(v);
    } else if (i < ZSEG_END) {
        int j = i - XSEG;                 // 3 h1 zero cells (full 7168 each)
        int per = j / 7168; int off = j - per * 7168;
        ws[H1OFF + per * H1P + 192 * 7168 + off] = 0;
    } else if (i < W2OFF) {
        // w1: [tap][nh][chunkh(128)*8+jj], chunkh = (quad*2+nq)*16+m
        int j = i - W1OFF;
        int tap = j >> 11; int r = j & 2047;
        int nh = r >> 10; int rr = r & 1023;
        int chunkh = rr >> 3, jj = rr & 7;
        int m = chunkh & 15, nq = (chunkh >> 4) & 1, quad = chunkh >> 5;
        int o = nh * 32 + nq * 16 + m, c = quad * 8 + jj;
        float v = 0.5f * w1_1[(o * 32 + c) * 81 + tap];
        if (tap == 40) v += 0.5f * w1_0[o * 32 + c];
        ws[i] = f2bf(v);
    } else if (i < PREP_N) {
        // w2: [tap][kh][chunkh(128)*8+jj], chunkh = (quad*2+nt)*16+m
        int j = i - W2OFF;
        int tap = j >> 11; int r = j & 2047;
        int kh = r >> 10; int rr = r & 1023;
        int chunkh = rr >> 3, jj = rr & 7;
        int m = chunkh & 15, nt = (chunkh >> 4) & 1, quad = chunkh >> 5;
        int o = nt * 16 + m, c = kh * 32 + quad * 8 + jj;
        float v = 0.5f * w2_1[(o * 64 + c) * 81 + tap];
        if (tap == 40) v += 0.5f * w2_0[o * 64 + c];
        ws[i] = f2bf(v);
    } else if (i < PREP_TOT) {
        int j = i - PREP_N;
        ((float4*)out)[j] = ((const float4*)x)[j];
    }
}

// cell index for (b, l2, q2): valid -> b*48 + l2*P + q2, else zero cell 192
template<int P>
__device__ __forceinline__ int cidx(int bb, int l2, int q2) {
    constexpr int L = 48 / P;
    return ((unsigned)l2 < (unsigned)L && (unsigned)q2 < (unsigned)P)
               ? bb * 48 + l2 * P + q2 : 192;
}

// ---- conv1 (C32 -> 32 of C64, nh half) + GELU.
// Block = 4 waves: (tloc, mh) = (wv>>1, wv&1). Depth-2 pipeline:
// 4-deep weight ring, wait-own-queue vmcnt BEFORE raw s_barrier. ----
template<int P>
__device__ __forceinline__ void conv1_body(
    const u16* __restrict__ xs, const u16* __restrict__ w1b,
    u16* __restrict__ h1, int tp, int bb, int nh,
    u16* __restrict__ s_w, u16* __restrict__ s_a) {
    constexpr int HB = (P == 2) ? 0 : (P == 3) ? H1P : 2 * H1P;

    int tid = threadIdx.x;
    int lane = tid & 63, wv = tid >> 6;
    int m = lane & 15, quad = lane >> 4;
    int tloc = wv >> 1, mh = wv & 1;

    int t0 = tp * 2, t1 = tp * 2 + 1;
    int l0 = t0 / P, q0 = t0 - l0 * P;
    int l1 = t1 / P, q1 = t1 - l1 * P;

    int sp[2];
#pragma unroll
    for (int mtl = 0; mtl < 2; ++mtl) {
        int pos = (mh * 2 + mtl) * 16 + m;
        sp[mtl] = (pos >> 3) * 10 + (pos & 7);
    }

    f32x4 acc[2][2];
#pragma unroll
    for (int mtl = 0; mtl < 2; ++mtl)
#pragma unroll
        for (int nq = 0; nq < 2; ++nq) acc[mtl][nq] = f32x4{0.f, 0.f, 0.f, 0.f};

    // weights chunk cgn = taps 3cgn..3cgn+2, this nh half: 6 pieces, pad 8
    // -> 2/wave uniform (k>=6 duplicates piece 5: same src+dst, benign)
    auto stageW = [&](int cgn) {
        const u16* src = w1b + (cgn * 3) * 2048 + nh * 1024;
        u16* dst = s_w + (cgn & 3) * 3072;
#pragma unroll
        for (int i = 0; i < 2; ++i) {
            int k = wv * 2 + i; if (k >= 6) k = 5;
            cp1k(src + (k >> 1) * 2048 + (k & 1) * 512, dst + k * 512, lane);
        }
    };
    // act group gg: 2 cells x 7 pieces = 14 padded to 16 -> 4/wave uniform
    auto stageA = [&](int gg) {
        int dl = gg / 3, dq = gg - (gg / 3) * 3;
        const u16* c0 = xs + cidx<P>(bb, l0 + dl - 1, q0 + dq - 1) * XC;
        const u16* c1 = xs + cidx<P>(bb, l1 + dl - 1, q1 + dq - 1) * XC;
#pragma unroll
        for (int i = 0; i < 4; ++i) {
            int k = wv * 4 + i; if (k >= 14) k = 13;
            int cell = k / 7, pc = k - (k / 7) * 7;
            cp1k((cell ? c1 : c0) + pc * 512,
                 s_a + (cell * 2 + (gg & 1)) * 3584 + pc * 512, lane);
        }
    };

    // prologue: chunks 0 (W+A0) and 1 (W). per-wave outstanding = 2+4+2
    stageW(0); stageA(0); stageW(1);

#pragma unroll 1
    for (int cg = 0; cg < 27; ++cg) {
        // issue chunk cg+2 (slot (cg+2)&3 distinct from readers cg-1,cg and
        // in-flight cg+1 under mod-4). A(g) rides with chunk 3g.
        if (cg < 25) {
            stageW(cg + 2);
            if ((cg + 2) % 3 == 0) stageA((cg + 2) / 3);
        }
        // wait own queue: chunk cg delivered; leave cg+1, cg+2 in flight.
        // P(chunk c) = 2 + (4 if c%3==0). cg%3==0 -> 4, else 8; tail 2, 0.
        if (cg == 25) { WAITVM(2); }
        else if (cg == 26) { WAITVM(0); }
        else if (cg % 3 == 0) { WAITVM(4); }
        else { WAITVM(8); }
        SBAR();   // publishes delivery of chunk cg + completion of cg-1

        int grp = cg / 3, part = cg - grp * 3;
        const u16* bw = s_w + (cg & 3) * 3072;
        const u16* ba = s_a + (tloc * 2 + (grp & 1)) * 3584;
        int dwb = part * 10;   // dw = part, dh = j
#pragma unroll
        for (int j = 0; j < 3; ++j) {
            const u16* tw = bw + j * 1024;
            bf16x8 wf[2];
#pragma unroll
            for (int nq = 0; nq < 2; ++nq)
                wf[nq] = *(const bf16x8*)(tw + (((quad * 2 + nq) * 16 + m) << 3));
            bf16x8 af[2];
#pragma unroll
            for (int mtl = 0; mtl < 2; ++mtl) {
                int cellpos = sp[mtl] + dwb + j;
                af[mtl] = *(const bf16x8*)(ba + cellpos * 32 +
                                           ((quad ^ (cellpos & 3)) << 3));
            }
#pragma unroll
            for (int mtl = 0; mtl < 2; ++mtl)
#pragma unroll
                for (int nq = 0; nq < 2; ++nq)
                    acc[mtl][nq] = __builtin_amdgcn_mfma_f32_16x16x32_bf16(
                        af[mtl], wf[nq], acc[mtl][nq], 0, 0, 0);
        }
    }

    // epilogue: GELU -> bf16 -> swizzled half-cell interior (x-cell-style)
    int t = tp * 2 + tloc;
    u16* hh = h1 + HB + (bb * 48 + t) * HC2 + nh * 3584;
#pragma unroll
    for (int mtl = 0; mtl < 2; ++mtl)
#pragma unroll
        for (int r = 0; r < 4; ++r) {
            int pos = (mh * 2 + mtl) * 16 + quad * 4 + r;
            int cellpos = ((pos >> 3) + 1) * 10 + (pos & 7) + 1;
#pragma unroll
            for (int nq = 0; nq < 2; ++nq) {
                int ol = nq * 16 + m;
                hh[cellpos * 32 + (((ol >> 3) ^ (cellpos & 3)) << 3) + (ol & 7)] =
                    f2bf(gelu_exact(acc[mtl][nq][r]));
            }
        }
    // zero the 36 border cellpos of both t half-cells (unique writer)
#pragma unroll
    for (int it = 0; it < 5; ++it) {
        int k = it * 256 + tid;
        if (k < 1152) {
            int tb = k >= 576; int rr = k - tb * 576;
            int bp = rr >> 4, u = rr & 15;
            int cp;
            if (bp < 10) cp = bp;
            else if (bp < 20) cp = 90 + (bp - 10);
            else if (bp < 28) cp = (bp - 19) * 10;
            else cp = (bp - 27) * 10 + 9;
            unsigned int* h32 = (unsigned int*)(h1 + HB +
                (bb * 48 + tp * 2 + tb) * HC2 + nh * 3584);
            h32[cp * 16 + u] = 0;
        }
    }
}

// ---- conv2 (32 of C64 -> C32 partial, kh half). Same structure/pipeline
// as conv1; epilogue atomicAdds acc/3 into out (pre-filled with x). ----
template<int P>
__device__ __forceinline__ void conv2_body(
    const u16* __restrict__ h1, const u16* __restrict__ w2b,
    float* __restrict__ out, int tp, int bb, int kh,
    u16* __restrict__ s_w, u16* __restrict__ s_a) {
    constexpr int HB = (P == 2) ? 0 : (P == 3) ? H1P : 2 * H1P;

    int tid = threadIdx.x;
    int lane = tid & 63, wv = tid >> 6;
    int m = lane & 15, quad = lane >> 4;
    int tloc = wv >> 1, mh = wv & 1;

    int t0 = tp * 2, t1 = tp * 2 + 1;
    int l0 = t0 / P, q0 = t0 - l0 * P;
    int l1 = t1 / P, q1 = t1 - l1 * P;
    const u16* hb = h1 + HB;

    int sp[2];
#pragma unroll
    for (int mtl = 0; mtl < 2; ++mtl) {
        int pos = (mh * 2 + mtl) * 16 + m;
        sp[mtl] = (pos >> 3) * 10 + (pos & 7);
    }

    f32x4 acc[2][2];
#pragma unroll
    for (int mtl = 0; mtl < 2; ++mtl)
#pragma unroll
        for (int nt = 0; nt < 2; ++nt) acc[mtl][nt] = f32x4{0.f, 0.f, 0.f, 0.f};

    auto stageW = [&](int cgn) {
        const u16* src = w2b + (cgn * 3) * 2048 + kh * 1024;
        u16* dst = s_w + (cgn & 3) * 3072;
#pragma unroll
        for (int i = 0; i < 2; ++i) {
            int k = wv * 2 + i; if (k >= 6) k = 5;
            cp1k(src + (k >> 1) * 2048 + (k & 1) * 512, dst + k * 512, lane);
        }
    };
    auto stageA = [&](int gg) {
        int dl = gg / 3, dq = gg - (gg / 3) * 3;
        const u16* c0 = hb + cidx<P>(bb, l0 + dl - 1, q0 + dq - 1) * HC2 + kh * 3584;
        const u16* c1 = hb + cidx<P>(bb, l1 + dl - 1, q1 + dq - 1) * HC2 + kh * 3584;
#pragma unroll
        for (int i = 0; i < 4; ++i) {
            int k = wv * 4 + i; if (k >= 14) k = 13;
            int cell = k / 7, pc = k - (k / 7) * 7;
            cp1k((cell ? c1 : c0) + pc * 512,
                 s_a + (cell * 2 + (gg & 1)) * 3584 + pc * 512, lane);
        }
    };

    stageW(0); stageA(0); stageW(1);

#pragma unroll 1
    for (int cg = 0; cg < 27; ++cg) {
        if (cg < 25) {
            stageW(cg + 2);
            if ((cg + 2) % 3 == 0) stageA((cg + 2) / 3);
        }
        if (cg == 25) { WAITVM(2); }
        else if (cg == 26) { WAITVM(0); }
        else if (cg % 3 == 0) { WAITVM(4); }
        else { WAITVM(8); }
        SBAR();

        int grp = cg / 3, part = cg - grp * 3;
        const u16* bw = s_w + (cg & 3) * 3072;
        const u16* ba = s_a + (tloc * 2 + (grp & 1)) * 3584;
        int dwb = part * 10;
#pragma unroll
        for (int j = 0; j < 3; ++j) {
            const u16* tw = bw + j * 1024;
            bf16x8 wf[2];
#pragma unroll
            for (int nt = 0; nt < 2; ++nt)
                wf[nt] = *(const bf16x8*)(tw + (((quad * 2 + nt) * 16 + m) << 3));
            bf16x8 af[2];
#pragma unroll
            for (int mtl = 0; mtl < 2; ++mtl) {
                int cellpos = sp[mtl] + dwb + j;
                af[mtl] = *(const bf16x8*)(ba + cellpos * 32 +
                                           ((quad ^ (cellpos & 3)) << 3));
            }
#pragma unroll
            for (int mtl = 0; mtl < 2; ++mtl)
#pragma unroll
                for (int nt = 0; nt < 2; ++nt)
                    acc[mtl][nt] = __builtin_amdgcn_mfma_f32_16x16x32_bf16(
                        af[mtl], wf[nt], acc[mtl][nt], 0, 0, 0);
        }
    }

    // epilogue: out += acc/3 (softmax(ones) weights); out pre-filled with x
    int t = tp * 2 + tloc;
    float* orow = out + (bb * 48 + t) * 2048;
    const float s = 1.0f / 3.0f;
#pragma unroll
    for (int mtl = 0; mtl < 2; ++mtl)
#pragma unroll
        for (int nt = 0; nt < 2; ++nt)
#pragma unroll
            for (int r = 0; r < 4; ++r) {
                int pos = (mh * 2 + mtl) * 16 + quad * 4 + r;
                atomicAdd(&orow[pos * 32 + nt * 16 + m], acc[mtl][nt][r] * s);
            }
}

// ---- fused conv1 -> group barrier -> conv2 ----
__global__ __launch_bounds__(256, 3) void conv_fused(
    const u16* __restrict__ ws_x, const u16* __restrict__ ws_w1,
    const u16* __restrict__ ws_w2, u16* __restrict__ ws_h1,
    float* __restrict__ out, unsigned* __restrict__ bar) {
    __shared__ __align__(16) u16 s_w[4 * 3072];   // 24 KB weight ring
    __shared__ __align__(16) u16 s_a[4 * 3584];   // 28 KB -> 52 KB, 3 blk/CU
    int g = blockIdx.x;
    int jid = (g & 7) * 72 + (g >> 3);            // XCD-chunked, 576 = 8*72
    int per = jid / 192; int rem = jid - per * 192;
    int bb = rem / 48; int r2 = rem - bb * 48;
    int tp = r2 >> 1, h = r2 & 1;

    if (per == 0)      conv1_body<2>(ws_x, ws_w1, ws_h1, tp, bb, h, s_w, s_a);
    else if (per == 1) conv1_body<3>(ws_x, ws_w1, ws_h1, tp, bb, h, s_w, s_a);
    else               conv1_body<4>(ws_x, ws_w1, ws_h1, tp, bb, h, s_w, s_a);

    // wait for exactly the 24 producers of h1 half h, period per, batch bb
    group_barrier(bar + (per * 8 + bb * 2 + h), 24u);

    if (per == 0)      conv2_body<2>(ws_h1, ws_w2, out, tp, bb, h, s_w, s_a);
    else if (per == 1) conv2_body<3>(ws_h1, ws_w2, out, tp, bb, h, s_w, s_a);
    else               conv2_body<4>(ws_h1, ws_w2, out, tp, bb, h, s_w, s_a);
}

extern "C" void kernel_launch(void* const* d_in, const int* in_sizes, int n_in,
                              void* d_out, int out_size, void* d_ws, size_t ws_size,
                              hipStream_t stream) {
    const float* x    = (const float*)d_in[0];
    const float* w1_0 = (const float*)d_in[1];
    const float* w1_1 = (const float*)d_in[2];
    const float* w2_0 = (const float*)d_in[3];
    const float* w2_1 = (const float*)d_in[4];
    float* out = (float*)d_out;

    u16* ws = (u16*)d_ws;
    u16* ws_x  = ws;                 // 193 cells (192 real + zero)
    u16* ws_w1 = ws + W1OFF;
    u16* ws_w2 = ws + W2OFF;
    u16* ws_h1 = ws + H1OFF;         // 3 x 193 cells x 7168
    unsigned* bar = (unsigned*)(ws + BAROFF);

    prep<<<(PREP_TOT + 255) / 256, 256, 0, stream>>>(
        x, w1_0, w1_1, w2_0, w2_1, ws, out);
    conv_fused<<<576, 256, 0, stream>>>(ws_x, ws_w1, ws_w2, ws_h1, out, bar);
}

// Round 3
// 131.130 us; speedup vs baseline: 1.3427x; 1.3427x over previous
//
#include <hip/hip_runtime.h>
#include <math.h>

// B=4, T=48, W=8, H=8, C=32; d_ff=64; periods {2,3,4}. T%P==0 always.
// (1x1 + 3^4)/2 inception folded into one 81-tap conv (center tap 40).
// R17 = R15 structure (split kernels; R16 fusion reverted: device-scope
// acquire fences invalidated L1/L2 576x and the group barrier won zero
// overlap) + weights moved LDS -> direct global->VGPR loads:
//   * wf fragments are identical addresses for all waves/blocks -> L1/L2 hit;
//     s_w ring + its vmcnt ladder deleted.
//   * phase structure 27 -> 9 (one per neighbor cell-pair, 9 taps = 36 MFMA
//     per phase, one WAITVM(0)+SBAR pair per phase).
//   * LDS 52 KB -> 28 KB; __launch_bounds__(256,4) -> 4 blk/CU, 16 waves/CU.

typedef __attribute__((ext_vector_type(8))) short bf16x8;
typedef __attribute__((ext_vector_type(4))) float f32x4;
typedef unsigned short u16;

// ---- workspace offsets (u16 units) ----
#define XC 3200                 // u16 per x cell (10*10*32)
#define HC2 7168                // u16 per h1 cell (2 halves x 3584, padded)
#define XSEG 617600             // 193 * XC   (cell 192 = zero cell)
#define ZSEG_END 639104         // + 3*7168 h1 zero-cell writes
#define W1OFF 639104            // 165888 bf16: [tap 0..80][nh(2)][1024]
#define W2OFF 804992            // 165888 bf16: [tap 0..80][kh(2)][1024]
#define H1OFF 970880            // 3 periods x 193 cells x 7168
#define H1P 1383424             // per-period stride = 193*7168
#define PREP_N 970880           // end of weight segment
#define OUT_Q 98304             // out-init float4 count (393216 fp32)
#define PREP_TOT (PREP_N + OUT_Q)

#define WAITVM(N) asm volatile("s_waitcnt vmcnt(" #N ")" ::: "memory")
#define SBAR()    asm volatile("s_barrier" ::: "memory")

__device__ __forceinline__ u16 f2bf(float f) {
    unsigned u = __float_as_uint(f);
    unsigned r = u + 0x7fffu + ((u >> 16) & 1u);
    return (u16)(r >> 16);
}
__device__ __forceinline__ float gelu_exact(float v) {
    return 0.5f * v * (1.0f + erff(v * 0.7071067811865476f));
}

// async copy of 1 KB: 64 lanes x 16 B. LDS dest = wave-uniform base + lane*16.
__device__ __forceinline__ void cp1k(const u16* g, u16* l, int lane) {
    __builtin_amdgcn_global_load_lds(
        (const __attribute__((address_space(1))) unsigned int*)(g + lane * 8),
        (__attribute__((address_space(3))) unsigned int*)(l + lane * 8),
        16, 0, 0);
}

// ---- prep: x cells (swizzled) + h1 zero cells + weights + out = x ----
__global__ __launch_bounds__(256) void prep(
    const float* __restrict__ x,
    const float* __restrict__ w1_0, const float* __restrict__ w1_1,
    const float* __restrict__ w2_0, const float* __restrict__ w2_1,
    u16* __restrict__ ws, float* __restrict__ out) {
    int i = blockIdx.x * 256 + threadIdx.x;
    if (i < XSEG) {
        int cellidx = i / XC; int inner = i - cellidx * XC;
        int cellpos = inner >> 5; int low = inner & 31;
        int sc = low >> 3, jj = low & 7;
        int c = ((sc ^ (cellpos & 3)) << 3) + jj;
        int wp = cellpos / 10, hp = cellpos - (cellpos / 10) * 10;
        float v = 0.f;
        if (cellidx < 192 && wp >= 1 && wp <= 8 && hp >= 1 && hp <= 8)
            v = x[(cellidx * 64 + (wp - 1) * 8 + (hp - 1)) * 32 + c];
        ws[i] = f2bf(v);
    } else if (i < ZSEG_END) {
        int j = i - XSEG;                 // 3 h1 zero cells (full 7168 each)
        int per = j / 7168; int off = j - per * 7168;
        ws[H1OFF + per * H1P + 192 * 7168 + off] = 0;
    } else if (i < W2OFF) {
        // w1: [tap][nh][chunkh(128)*8+jj], chunkh = (quad*2+nq)*16+m
        int j = i - W1OFF;
        int tap = j >> 11; int r = j & 2047;
        int nh = r >> 10; int rr = r & 1023;
        int chunkh = rr >> 3, jj = rr & 7;
        int m = chunkh & 15, nq = (chunkh >> 4) & 1, quad = chunkh >> 5;
        int o = nh * 32 + nq * 16 + m, c = quad * 8 + jj;
        float v = 0.5f * w1_1[(o * 32 + c) * 81 + tap];
        if (tap == 40) v += 0.5f * w1_0[o * 32 + c];
        ws[i] = f2bf(v);
    } else if (i < PREP_N) {
        // w2: [tap][kh][chunkh(128)*8+jj], chunkh = (quad*2+nt)*16+m
        int j = i - W2OFF;
        int tap = j >> 11; int r = j & 2047;
        int kh = r >> 10; int rr = r & 1023;
        int chunkh = rr >> 3, jj = rr & 7;
        int m = chunkh & 15, nt = (chunkh >> 4) & 1, quad = chunkh >> 5;
        int o = nt * 16 + m, c = kh * 32 + quad * 8 + jj;
        float v = 0.5f * w2_1[(o * 64 + c) * 81 + tap];
        if (tap == 40) v += 0.5f * w2_0[o * 64 + c];
        ws[i] = f2bf(v);
    } else if (i < PREP_TOT) {
        int j = i - PREP_N;
        ((float4*)out)[j] = ((const float4*)x)[j];
    }
}

// cell index for (b, l2, q2): valid -> b*48 + l2*P + q2, else zero cell 192
template<int P>
__device__ __forceinline__ int cidx(int bb, int l2, int q2) {
    constexpr int L = 48 / P;
    return ((unsigned)l2 < (unsigned)L && (unsigned)q2 < (unsigned)P)
               ? bb * 48 + l2 * P + q2 : 192;
}

// ---- conv1 (C32 -> 32 of C64, nh half) + GELU.
// Block = 4 waves: (tloc, mh) = (wv>>1, wv&1). 9 phases (one per neighbor
// cell-pair): stage next act group, 9 taps x 4 MFMA, weights global->VGPR. --
template<int P>
__device__ __forceinline__ void conv1_body(
    const u16* __restrict__ xs, const u16* __restrict__ w1b,
    u16* __restrict__ h1, int tp, int bb, int nh,
    u16* __restrict__ s_a) {
    constexpr int HB = (P == 2) ? 0 : (P == 3) ? H1P : 2 * H1P;

    int tid = threadIdx.x;
    int lane = tid & 63, wv = tid >> 6;
    int m = lane & 15, quad = lane >> 4;
    int tloc = wv >> 1, mh = wv & 1;

    int t0 = tp * 2, t1 = tp * 2 + 1;
    int l0 = t0 / P, q0 = t0 - l0 * P;
    int l1 = t1 / P, q1 = t1 - l1 * P;

    int sp[2];
#pragma unroll
    for (int mtl = 0; mtl < 2; ++mtl) {
        int pos = (mh * 2 + mtl) * 16 + m;
        sp[mtl] = (pos >> 3) * 10 + (pos & 7);
    }

    f32x4 acc[2][2];
#pragma unroll
    for (int mtl = 0; mtl < 2; ++mtl)
#pragma unroll
        for (int nq = 0; nq < 2; ++nq) acc[mtl][nq] = f32x4{0.f, 0.f, 0.f, 0.f};

    // per-lane weight base: nq fragment at +128 u16, tap stride 2048 u16
    const u16* wlane = w1b + nh * 1024 + ((quad * 32 + m) << 3);

    // act group gg: 2 cells x 7 pieces = 14 padded to 16 -> 4/wave uniform
    auto stageA = [&](int gg) {
        int dl = gg / 3, dq = gg - (gg / 3) * 3;
        const u16* c0 = xs + cidx<P>(bb, l0 + dl - 1, q0 + dq - 1) * XC;
        const u16* c1 = xs + cidx<P>(bb, l1 + dl - 1, q1 + dq - 1) * XC;
#pragma unroll
        for (int i = 0; i < 4; ++i) {
            int k = wv * 4 + i; if (k >= 14) k = 13;
            int cell = k / 7, pc = k - (k / 7) * 7;
            cp1k((cell ? c1 : c0) + pc * 512,
                 s_a + (cell * 2 + (gg & 1)) * 3584 + pc * 512, lane);
        }
    };

    stageA(0);
    WAITVM(0); SBAR();

#pragma unroll 1
    for (int gg = 0; gg < 9; ++gg) {
        // slot (gg+1)&1 was last read in phase gg-1 (done at entry barrier);
        // delivery checked by WAITVM(0)+SBAR at end of this phase.
        if (gg < 8) stageA(gg + 1);

        const u16* ba = s_a + (tloc * 2 + (gg & 1)) * 3584;
        const u16* wgg = wlane + gg * 9 * 2048;
#pragma unroll
        for (int pj = 0; pj < 9; ++pj) {
            int part = pj / 3, j = pj - (pj / 3) * 3;   // dw, dh
            const u16* tw = wgg + pj * 2048;
            bf16x8 wf[2];
            wf[0] = *(const bf16x8*)(tw);
            wf[1] = *(const bf16x8*)(tw + 128);
            bf16x8 af[2];
#pragma unroll
            for (int mtl = 0; mtl < 2; ++mtl) {
                int cellpos = sp[mtl] + part * 10 + j;
                af[mtl] = *(const bf16x8*)(ba + cellpos * 32 +
                                           ((quad ^ (cellpos & 3)) << 3));
            }
#pragma unroll
            for (int mtl = 0; mtl < 2; ++mtl)
#pragma unroll
                for (int nq = 0; nq < 2; ++nq)
                    acc[mtl][nq] = __builtin_amdgcn_mfma_f32_16x16x32_bf16(
                        af[mtl], wf[nq], acc[mtl][nq], 0, 0, 0);
        }
        if (gg < 8) { WAITVM(0); SBAR(); }   // own A(gg+1) delivered; publish
    }

    // epilogue: GELU -> bf16 -> swizzled half-cell interior (x-cell-style)
    int t = tp * 2 + tloc;
    u16* hh = h1 + HB + (bb * 48 + t) * HC2 + nh * 3584;
#pragma unroll
    for (int mtl = 0; mtl < 2; ++mtl)
#pragma unroll
        for (int r = 0; r < 4; ++r) {
            int pos = (mh * 2 + mtl) * 16 + quad * 4 + r;
            int cellpos = ((pos >> 3) + 1) * 10 + (pos & 7) + 1;
#pragma unroll
            for (int nq = 0; nq < 2; ++nq) {
                int ol = nq * 16 + m;
                hh[cellpos * 32 + (((ol >> 3) ^ (cellpos & 3)) << 3) + (ol & 7)] =
                    f2bf(gelu_exact(acc[mtl][nq][r]));
            }
        }
    // zero the 36 border cellpos of both t half-cells (unique writer)
#pragma unroll
    for (int it = 0; it < 5; ++it) {
        int k = it * 256 + tid;
        if (k < 1152) {
            int tb = k >= 576; int rr = k - tb * 576;
            int bp = rr >> 4, u = rr & 15;
            int cp;
            if (bp < 10) cp = bp;
            else if (bp < 20) cp = 90 + (bp - 10);
            else if (bp < 28) cp = (bp - 19) * 10;
            else cp = (bp - 27) * 10 + 9;
            unsigned int* h32 = (unsigned int*)(h1 + HB +
                (bb * 48 + tp * 2 + tb) * HC2 + nh * 3584);
            h32[cp * 16 + u] = 0;
        }
    }
}

__global__ __launch_bounds__(256, 4) void conv1_k(
    const u16* __restrict__ ws_x, const u16* __restrict__ ws_w1,
    u16* __restrict__ ws_h1) {
    __shared__ __align__(16) u16 s_a[4 * 3584];   // 28 KB -> 4 blk/CU
    int g = blockIdx.x;
    int jid = (g & 7) * 72 + (g >> 3);            // XCD-chunked, 576 = 8*72
    int per = jid / 192; int rem = jid - per * 192;
    int bb = rem / 48; int r2 = rem - bb * 48;
    int tp = r2 >> 1, nh = r2 & 1;
    if (per == 0)      conv1_body<2>(ws_x, ws_w1, ws_h1, tp, bb, nh, s_a);
    else if (per == 1) conv1_body<3>(ws_x, ws_w1, ws_h1, tp, bb, nh, s_a);
    else               conv1_body<4>(ws_x, ws_w1, ws_h1, tp, bb, nh, s_a);
}

// ---- conv2 (32 of C64 -> C32 partial, kh half). Same 9-phase structure;
// epilogue atomicAdds acc/3 into out (pre-filled with x). ----
template<int P>
__device__ __forceinline__ void conv2_body(
    const u16* __restrict__ h1, const u16* __restrict__ w2b,
    float* __restrict__ out, int tp, int bb, int kh,
    u16* __restrict__ s_a) {
    constexpr int HB = (P == 2) ? 0 : (P == 3) ? H1P : 2 * H1P;

    int tid = threadIdx.x;
    int lane = tid & 63, wv = tid >> 6;
    int m = lane & 15, quad = lane >> 4;
    int tloc = wv >> 1, mh = wv & 1;

    int t0 = tp * 2, t1 = tp * 2 + 1;
    int l0 = t0 / P, q0 = t0 - l0 * P;
    int l1 = t1 / P, q1 = t1 - l1 * P;
    const u16* hb = h1 + HB;

    int sp[2];
#pragma unroll
    for (int mtl = 0; mtl < 2; ++mtl) {
        int pos = (mh * 2 + mtl) * 16 + m;
        sp[mtl] = (pos >> 3) * 10 + (pos & 7);
    }

    f32x4 acc[2][2];
#pragma unroll
    for (int mtl = 0; mtl < 2; ++mtl)
#pragma unroll
        for (int nt = 0; nt < 2; ++nt) acc[mtl][nt] = f32x4{0.f, 0.f, 0.f, 0.f};

    const u16* wlane = w2b + kh * 1024 + ((quad * 32 + m) << 3);

    auto stageA = [&](int gg) {
        int dl = gg / 3, dq = gg - (gg / 3) * 3;
        const u16* c0 = hb + cidx<P>(bb, l0 + dl - 1, q0 + dq - 1) * HC2 + kh * 3584;
        const u16* c1 = hb + cidx<P>(bb, l1 + dl - 1, q1 + dq - 1) * HC2 + kh * 3584;
#pragma unroll
        for (int i = 0; i < 4; ++i) {
            int k = wv * 4 + i; if (k >= 14) k = 13;
            int cell = k / 7, pc = k - (k / 7) * 7;
            cp1k((cell ? c1 : c0) + pc * 512,
                 s_a + (cell * 2 + (gg & 1)) * 3584 + pc * 512, lane);
        }
    };

    stageA(0);
    WAITVM(0); SBAR();

#pragma unroll 1
    for (int gg = 0; gg < 9; ++gg) {
        if (gg < 8) stageA(gg + 1);

        const u16* ba = s_a + (tloc * 2 + (gg & 1)) * 3584;
        const u16* wgg = wlane + gg * 9 * 2048;
#pragma unroll
        for (int pj = 0; pj < 9; ++pj) {
            int part = pj / 3, j = pj - (pj / 3) * 3;
            const u16* tw = wgg + pj * 2048;
            bf16x8 wf[2];
            wf[0] = *(const bf16x8*)(tw);
            wf[1] = *(const bf16x8*)(tw + 128);
            bf16x8 af[2];
#pragma unroll
            for (int mtl = 0; mtl < 2; ++mtl) {
                int cellpos = sp[mtl] + part * 10 + j;
                af[mtl] = *(const bf16x8*)(ba + cellpos * 32 +
                                           ((quad ^ (cellpos & 3)) << 3));
            }
#pragma unroll
            for (int mtl = 0; mtl < 2; ++mtl)
#pragma unroll
                for (int nt = 0; nt < 2; ++nt)
                    acc[mtl][nt] = __builtin_amdgcn_mfma_f32_16x16x32_bf16(
                        af[mtl], wf[nt], acc[mtl][nt], 0, 0, 0);
        }
        if (gg < 8) { WAITVM(0); SBAR(); }
    }

    // epilogue: out += acc/3 (softmax(ones) weights); out pre-filled with x
    int t = tp * 2 + tloc;
    float* orow = out + (bb * 48 + t) * 2048;
    const float s = 1.0f / 3.0f;
#pragma unroll
    for (int mtl = 0; mtl < 2; ++mtl)
#pragma unroll
        for (int nt = 0; nt < 2; ++nt)
#pragma unroll
            for (int r = 0; r < 4; ++r) {
                int pos = (mh * 2 + mtl) * 16 + quad * 4 + r;
                atomicAdd(&orow[pos * 32 + nt * 16 + m], acc[mtl][nt][r] * s);
            }
}

__global__ __launch_bounds__(256, 4) void conv2_k(
    const u16* __restrict__ ws_h1, const u16* __restrict__ ws_w2,
    float* __restrict__ out) {
    __shared__ __align__(16) u16 s_a[4 * 3584];   // 28 KB -> 4 blk/CU
    int g = blockIdx.x;
    int jid = (g & 7) * 72 + (g >> 3);            // same XCD mapping as conv1
    int per = jid / 192; int rem = jid - per * 192;
    int bb = rem / 48; int r2 = rem - bb * 48;
    int tp = r2 >> 1, kh = r2 & 1;
    if (per == 0)      conv2_body<2>(ws_h1, ws_w2, out, tp, bb, kh, s_a);
    else if (per == 1) conv2_body<3>(ws_h1, ws_w2, out, tp, bb, kh, s_a);
    else               conv2_body<4>(ws_h1, ws_w2, out, tp, bb, kh, s_a);
}

extern "C" void kernel_launch(void* const* d_in, const int* in_sizes, int n_in,
                              void* d_out, int out_size, void* d_ws, size_t ws_size,
                              hipStream_t stream) {
    const float* x    = (const float*)d_in[0];
    const float* w1_0 = (const float*)d_in[1];
    const float* w1_1 = (const float*)d_in[2];
    const float* w2_0 = (const float*)d_in[3];
    const float* w2_1 = (const float*)d_in[4];
    float* out = (float*)d_out;

    u16* ws = (u16*)d_ws;
    u16* ws_x  = ws;                 // 193 cells (192 real + zero)
    u16* ws_w1 = ws + W1OFF;
    u16* ws_w2 = ws + W2OFF;
    u16* ws_h1 = ws + H1OFF;         // 3 x 193 cells x 7168

    prep<<<(PREP_TOT + 255) / 256, 256, 0, stream>>>(
        x, w1_0, w1_1, w2_0, w2_1, ws, out);
    conv1_k<<<576, 256, 0, stream>>>(ws_x, ws_w1, ws_h1);
    conv2_k<<<576, 256, 0, stream>>>(ws_h1, ws_w2, out);
}

// Round 4
// 124.608 us; speedup vs baseline: 1.4130x; 1.0523x over previous
//
#include <hip/hip_runtime.h>
#include <math.h>

// B=4, T=48, W=8, H=8, C=32; d_ff=64; periods {2,3,4}. T%P==0 always.
// (1x1 + 3^4)/2 inception folded into one 81-tap conv (center tap 40).
// R18 = R15 structure + PERIOD FUSION inside each block:
//   * blocks (bb,tp,half) = 192 per conv; all 3 periods computed per block
//     -> weight stream amortized 3x, 36 MFMA/wave/phase (was 12),
//     conv2 atomics 3x fewer (periods summed in-register).
//   * conv1: 12-cell absolute-t act window [t0-5,t0+6] (+zero slot) serves
//     ALL periods' neighborhoods -> acts staged ONCE in prologue (static,
//     91 KB LDS); main loop streams only the weight ring (mod-4, depth-2)
//     with traced vmcnt ladder D=4/2/0.
//   * conv2: per-period h1 acts double-buffered (6 half-cells/group),
//     staged at part==1 (WAR-safe past SBAR@3g), ladder D=4/16/16, tail
//     4/2/0 (traced in comments).
//   * R17's global->VGPR weights reverted (per-phase load-latency chain).

typedef __attribute__((ext_vector_type(8))) short bf16x8;
typedef __attribute__((ext_vector_type(4))) float f32x4;
typedef unsigned short u16;

// ---- workspace offsets (u16 units) ----
#define XC 3200                 // u16 per x cell (10*10*32)
#define HC2 7168                // u16 per h1 cell (2 halves x 3584)
#define XSEG 617600             // 193 * XC   (cell 192 = zero cell)
#define ZSEG_END 639104         // + 3*7168 h1 zero-cell writes
#define W1OFF 639104            // 165888 bf16: [tap 0..80][nh(2)][1024]
#define W2OFF 804992            // 165888 bf16: [tap 0..80][kh(2)][1024]
#define H1OFF 970880            // 3 periods x 193 cells x 7168
#define H1P 1383424             // per-period stride = 193*7168
#define PREP_N 970880           // end of weight segment
#define OUT_Q 98304             // out-init float4 count (393216 fp32)
#define PREP_TOT (PREP_N + OUT_Q)

#define WAITVM(N) asm volatile("s_waitcnt vmcnt(" #N ")" ::: "memory")
#define SBAR()    asm volatile("s_barrier" ::: "memory")

__device__ __forceinline__ u16 f2bf(float f) {
    unsigned u = __float_as_uint(f);
    unsigned r = u + 0x7fffu + ((u >> 16) & 1u);
    return (u16)(r >> 16);
}
__device__ __forceinline__ float gelu_exact(float v) {
    return 0.5f * v * (1.0f + erff(v * 0.7071067811865476f));
}

// async copy of 1 KB: 64 lanes x 16 B. LDS dest = wave-uniform base + lane*16.
__device__ __forceinline__ void cp1k(const u16* g, u16* l, int lane) {
    __builtin_amdgcn_global_load_lds(
        (const __attribute__((address_space(1))) unsigned int*)(g + lane * 8),
        (__attribute__((address_space(3))) unsigned int*)(l + lane * 8),
        16, 0, 0);
}

// ---- prep: x cells (swizzled) + h1 zero cells + weights + out = x ----
__global__ __launch_bounds__(256) void prep(
    const float* __restrict__ x,
    const float* __restrict__ w1_0, const float* __restrict__ w1_1,
    const float* __restrict__ w2_0, const float* __restrict__ w2_1,
    u16* __restrict__ ws, float* __restrict__ out) {
    int i = blockIdx.x * 256 + threadIdx.x;
    if (i < XSEG) {
        int cellidx = i / XC; int inner = i - cellidx * XC;
        int cellpos = inner >> 5; int low = inner & 31;
        int sc = low >> 3, jj = low & 7;
        int c = ((sc ^ (cellpos & 3)) << 3) + jj;
        int wp = cellpos / 10, hp = cellpos - (cellpos / 10) * 10;
        float v = 0.f;
        if (cellidx < 192 && wp >= 1 && wp <= 8 && hp >= 1 && hp <= 8)
            v = x[(cellidx * 64 + (wp - 1) * 8 + (hp - 1)) * 32 + c];
        ws[i] = f2bf(v);
    } else if (i < ZSEG_END) {
        int j = i - XSEG;                 // 3 h1 zero cells (full 7168 each)
        int per = j / 7168; int off = j - per * 7168;
        ws[H1OFF + per * H1P + 192 * 7168 + off] = 0;
    } else if (i < W2OFF) {
        // w1: [tap][nh][chunkh(128)*8+jj], chunkh = (quad*2+nq)*16+m
        int j = i - W1OFF;
        int tap = j >> 11; int r = j & 2047;
        int nh = r >> 10; int rr = r & 1023;
        int chunkh = rr >> 3, jj = rr & 7;
        int m = chunkh & 15, nq = (chunkh >> 4) & 1, quad = chunkh >> 5;
        int o = nh * 32 + nq * 16 + m, c = quad * 8 + jj;
        float v = 0.5f * w1_1[(o * 32 + c) * 81 + tap];
        if (tap == 40) v += 0.5f * w1_0[o * 32 + c];
        ws[i] = f2bf(v);
    } else if (i < PREP_N) {
        // w2: [tap][kh][chunkh(128)*8+jj], chunkh = (quad*2+nt)*16+m
        int j = i - W2OFF;
        int tap = j >> 11; int r = j & 2047;
        int kh = r >> 10; int rr = r & 1023;
        int chunkh = rr >> 3, jj = rr & 7;
        int m = chunkh & 15, nt = (chunkh >> 4) & 1, quad = chunkh >> 5;
        int o = nt * 16 + m, c = kh * 32 + quad * 8 + jj;
        float v = 0.5f * w2_1[(o * 64 + c) * 81 + tap];
        if (tap == 40) v += 0.5f * w2_0[o * 64 + c];
        ws[i] = f2bf(v);
    } else if (i < PREP_TOT) {
        int j = i - PREP_N;
        ((float4*)out)[j] = ((const float4*)x)[j];
    }
}

// ---- conv1 (C32 -> 32 of C64, nh half) x 3 periods + GELU.
// Block = (bb,tp,nh), 4 waves (tloc, mh). Acts: 13 static LDS slots
// (window t0-5..t0+6 + zero). Main loop: weight ring only, 27 phases,
// 36 MFMA/wave/phase. ----
__global__ __launch_bounds__(256) void conv1_k(
    const u16* __restrict__ ws_x, const u16* __restrict__ ws_w1,
    u16* __restrict__ ws_h1) {
    __shared__ __align__(16) u16 s_a[13 * 3584];   // 91 KB static acts
    __shared__ __align__(16) u16 s_w[4 * 3072];    // 24 KB weight ring
    int g = blockIdx.x;
    int jid = (g & 7) * 24 + (g >> 3);             // XCD-chunked, 192 = 8*24
    int bb = jid / 48; int rem = jid - bb * 48;
    int tp = rem >> 1, nh = rem & 1;
    int tid = threadIdx.x, lane = tid & 63, wv = tid >> 6;
    int m = lane & 15, quad = lane >> 4;
    int tloc = wv >> 1, mh = wv & 1;
    int t0 = tp * 2, t = t0 + tloc;

    int sp[2];
#pragma unroll
    for (int mtl = 0; mtl < 2; ++mtl) {
        int pos = (mh * 2 + mtl) * 16 + m;
        sp[mtl] = (pos >> 3) * 10 + (pos & 7);
    }

    f32x4 acc[3][2][2];
#pragma unroll
    for (int pi = 0; pi < 3; ++pi)
#pragma unroll
        for (int mtl = 0; mtl < 2; ++mtl)
#pragma unroll
            for (int nq = 0; nq < 2; ++nq)
                acc[pi][mtl][nq] = f32x4{0.f, 0.f, 0.f, 0.f};

    // weight chunk cgn = taps 3cgn..3cgn+2, nh half (6 pieces, 2/wave)
    auto stageW = [&](int cgn) {
        const u16* src = ws_w1 + (cgn * 3) * 2048 + nh * 1024;
        u16* dst = s_w + (cgn & 3) * 3072;
#pragma unroll
        for (int i = 0; i < 2; ++i) {
            int k = wv * 2 + i; if (k >= 6) k = 5;
            cp1k(src + (k >> 1) * 2048 + (k & 1) * 512, dst + k * 512, lane);
        }
    };

    // prologue: stage all 13 act slots (7 pieces each, 2/wave w/ dup) + W0,W1
    {
        int p0 = wv * 2; int p1 = (p0 + 1 > 6) ? 6 : p0 + 1;
#pragma unroll
        for (int s = 0; s < 13; ++s) {
            int tt = t0 - 5 + s;
            int cell = (s == 12) ? 192
                     : (((unsigned)tt < 48u) ? bb * 48 + tt : 192);
            const u16* sc = ws_x + cell * XC;
            u16* dc = s_a + s * 3584;
            cp1k(sc + p0 * 512, dc + p0 * 512, lane);
            cp1k(sc + p1 * 512, dc + p1 * 512, lane);
        }
    }
    stageW(0); stageW(1);
    WAITVM(2); SBAR();     // acts + W0 delivered (W1 stays in flight)

#pragma unroll 1
    for (int cg = 0; cg < 27; ++cg) {
        if (cg < 25) stageW(cg + 2);
        // D(cg) = ops newer than W(cg): W(cg+1)+W(cg+2) = 4; tail 2, 0.
        if (cg < 25)       { WAITVM(4); }
        else if (cg == 25) { WAITVM(2); }
        else               { WAITVM(0); }
        SBAR();

        int grp = cg / 3, part = cg - grp * 3;
        int dl = grp / 3, dq = grp - dl * 3;
        const u16* bw = s_w + (cg & 3) * 3072;
        const u16* bap[3];
#pragma unroll
        for (int pi = 0; pi < 3; ++pi) {
            const int P = pi + 2; const int L = 48 / P;
            int l = t / P, q = t - l * P;
            int lq = l + dl - 1, qq = q + dq - 1;
            int slot = ((unsigned)lq < (unsigned)L && (unsigned)qq < (unsigned)P)
                       ? (tloc + (dl - 1) * P + dq + 4) : 12;
            bap[pi] = s_a + slot * 3584;
        }
        int dwb = part * 10;
#pragma unroll
        for (int j = 0; j < 3; ++j) {
            const u16* tw = bw + j * 1024;
            bf16x8 wf0 = *(const bf16x8*)(tw + (((quad * 2 + 0) * 16 + m) << 3));
            bf16x8 wf1 = *(const bf16x8*)(tw + (((quad * 2 + 1) * 16 + m) << 3));
#pragma unroll
            for (int pi = 0; pi < 3; ++pi) {
#pragma unroll
                for (int mtl = 0; mtl < 2; ++mtl) {
                    int cellpos = sp[mtl] + dwb + j;
                    bf16x8 af = *(const bf16x8*)(bap[pi] + cellpos * 32 +
                                                 ((quad ^ (cellpos & 3)) << 3));
                    acc[pi][mtl][0] = __builtin_amdgcn_mfma_f32_16x16x32_bf16(
                        af, wf0, acc[pi][mtl][0], 0, 0, 0);
                    acc[pi][mtl][1] = __builtin_amdgcn_mfma_f32_16x16x32_bf16(
                        af, wf1, acc[pi][mtl][1], 0, 0, 0);
                }
            }
        }
    }

    // epilogue x3 periods: GELU -> bf16 -> swizzled half-cell interior
#pragma unroll
    for (int pi = 0; pi < 3; ++pi) {
        u16* hh = ws_h1 + pi * H1P + (bb * 48 + t) * HC2 + nh * 3584;
#pragma unroll
        for (int mtl = 0; mtl < 2; ++mtl)
#pragma unroll
            for (int r = 0; r < 4; ++r) {
                int pos = (mh * 2 + mtl) * 16 + quad * 4 + r;
                int cellpos = ((pos >> 3) + 1) * 10 + (pos & 7) + 1;
#pragma unroll
                for (int nq = 0; nq < 2; ++nq) {
                    int ol = nq * 16 + m;
                    hh[cellpos * 32 + (((ol >> 3) ^ (cellpos & 3)) << 3) + (ol & 7)] =
                        f2bf(gelu_exact(acc[pi][mtl][nq][r]));
                }
            }
    }
    // zero the 36 border cellpos of both t half-cells, all periods
#pragma unroll
    for (int pi = 0; pi < 3; ++pi) {
#pragma unroll
        for (int it = 0; it < 5; ++it) {
            int k = it * 256 + tid;
            if (k < 1152) {
                int tb = k >= 576; int rr = k - tb * 576;
                int bp = rr >> 4, u = rr & 15;
                int cp;
                if (bp < 10) cp = bp;
                else if (bp < 20) cp = 90 + (bp - 10);
                else if (bp < 28) cp = (bp - 19) * 10;
                else cp = (bp - 27) * 10 + 9;
                unsigned int* h32 = (unsigned int*)(ws_h1 + pi * H1P +
                    (bb * 48 + tp * 2 + tb) * HC2 + nh * 3584);
                h32[cp * 16 + u] = 0;
            }
        }
    }
}

// ---- conv2 (32 of C64 -> C32 partial, kh half) x 3 periods.
// Block = (bb,tp,kh), 4 waves (tloc, mh). Acts double-buffered per group
// (6 half-cells: 3 per x 2 sites), staged at part==1 (WAR-safe: previous
// parity readers done before SBAR@3g, issue is after it).
// Ladder trace (A=12/wave, W=2/wave):
//   p0: need A(grp)+W(3g); newer-than-A(grp)@(g-1,1) = W(3g+1)+W(3g+2) -> 4
//   p1: need W(3g+1); newer = W(3g+2)+W(3g+3)+A(g+1) -> 16
//   p2: need W(3g+2); newer = W(3g+3)+A(g+1)+W(3g+4) -> 16
//   cg=24 -> 4 (A(8)@22 older than W(24)@22? no: W-first order -> D=4 ok),
//   cg=25 -> 2, cg=26 -> 0.
// Epilogue: periods summed in-register, ONE atomicAdd(acc/3) per element. ----
__global__ __launch_bounds__(256) void conv2_k(
    const u16* __restrict__ ws_h1, const u16* __restrict__ ws_w2,
    float* __restrict__ out) {
    __shared__ __align__(16) u16 s_a[12 * 3584];   // 84 KB (2 x 6 half-cells)
    __shared__ __align__(16) u16 s_w[4 * 3072];    // 24 KB weight ring
    int g = blockIdx.x;
    int jid = (g & 7) * 24 + (g >> 3);             // XCD-chunked, 192 = 8*24
    int bb = jid / 48; int rem = jid - bb * 48;
    int tp = rem >> 1, kh = rem & 1;
    int tid = threadIdx.x, lane = tid & 63, wv = tid >> 6;
    int m = lane & 15, quad = lane >> 4;
    int tloc = wv >> 1, mh = wv & 1;
    int t0 = tp * 2, t = t0 + tloc;

    int sp[2];
#pragma unroll
    for (int mtl = 0; mtl < 2; ++mtl) {
        int pos = (mh * 2 + mtl) * 16 + m;
        sp[mtl] = (pos >> 3) * 10 + (pos & 7);
    }

    f32x4 acc[3][2][2];
#pragma unroll
    for (int pi = 0; pi < 3; ++pi)
#pragma unroll
        for (int mtl = 0; mtl < 2; ++mtl)
#pragma unroll
            for (int nt = 0; nt < 2; ++nt)
                acc[pi][mtl][nt] = f32x4{0.f, 0.f, 0.f, 0.f};

    auto stageW = [&](int cgn) {
        const u16* src = ws_w2 + (cgn * 3) * 2048 + kh * 1024;
        u16* dst = s_w + (cgn & 3) * 3072;
#pragma unroll
        for (int i = 0; i < 2; ++i) {
            int k = wv * 2 + i; if (k >= 6) k = 5;
            cp1k(src + (k >> 1) * 2048 + (k & 1) * 512, dst + k * 512, lane);
        }
    };
    // act group gg: 6 half-cells (per,site), 8 padded pieces each -> 12/wave
    auto stageA = [&](int gg) {
        int dl = gg / 3, dq = gg - (gg / 3) * 3;
        u16* dstb = s_a + (gg & 1) * (6 * 3584);
        int p0 = wv * 2; int p1 = (p0 + 1 > 6) ? 6 : p0 + 1;
#pragma unroll
        for (int c = 0; c < 6; ++c) {
            const int pi = c >> 1, st = c & 1;
            const int P = pi + 2, L = 48 / P;
            int ts = t0 + st;
            int l = ts / P, q = ts - l * P;
            int lq = l + dl - 1, qq = q + dq - 1;
            int cell = ((unsigned)lq < (unsigned)L && (unsigned)qq < (unsigned)P)
                       ? bb * 48 + lq * P + qq : 192;
            const u16* sc = ws_h1 + pi * H1P + cell * HC2 + kh * 3584;
            u16* dc = dstb + c * 3584;
            cp1k(sc + p0 * 512, dc + p0 * 512, lane);
            cp1k(sc + p1 * 512, dc + p1 * 512, lane);
        }
    };

    // prologue: A(0) then W(0), W(1); wait leaves W(1) in flight
    stageA(0); stageW(0); stageW(1);
    WAITVM(2); SBAR();

#pragma unroll 1
    for (int cg = 0; cg < 27; ++cg) {
        int grp = cg / 3, part = cg - grp * 3;
        if (cg < 25) stageW(cg + 2);
        if (part == 1 && grp < 8) stageA(grp + 1);
        if (cg == 26)      { WAITVM(0); }
        else if (cg == 25) { WAITVM(2); }
        else if (part == 0){ WAITVM(4); }
        else               { WAITVM(16); }
        SBAR();

        const u16* bw = s_w + (cg & 3) * 3072;
        const u16* bap[3];
#pragma unroll
        for (int pi = 0; pi < 3; ++pi)
            bap[pi] = s_a + ((grp & 1) * 6 + pi * 2 + tloc) * 3584;
        int dwb = part * 10;
#pragma unroll
        for (int j = 0; j < 3; ++j) {
            const u16* tw = bw + j * 1024;
            bf16x8 wf0 = *(const bf16x8*)(tw + (((quad * 2 + 0) * 16 + m) << 3));
            bf16x8 wf1 = *(const bf16x8*)(tw + (((quad * 2 + 1) * 16 + m) << 3));
#pragma unroll
            for (int pi = 0; pi < 3; ++pi) {
#pragma unroll
                for (int mtl = 0; mtl < 2; ++mtl) {
                    int cellpos = sp[mtl] + dwb + j;
                    bf16x8 af = *(const bf16x8*)(bap[pi] + cellpos * 32 +
                                                 ((quad ^ (cellpos & 3)) << 3));
                    acc[pi][mtl][0] = __builtin_amdgcn_mfma_f32_16x16x32_bf16(
                        af, wf0, acc[pi][mtl][0], 0, 0, 0);
                    acc[pi][mtl][1] = __builtin_amdgcn_mfma_f32_16x16x32_bf16(
                        af, wf1, acc[pi][mtl][1], 0, 0, 0);
                }
            }
        }
    }

    // epilogue: out += (sum over periods)/3 ; out pre-filled with x
    float* orow = out + (bb * 48 + t) * 2048;
    const float s = 1.0f / 3.0f;
#pragma unroll
    for (int mtl = 0; mtl < 2; ++mtl)
#pragma unroll
        for (int nt = 0; nt < 2; ++nt)
#pragma unroll
            for (int r = 0; r < 4; ++r) {
                int pos = (mh * 2 + mtl) * 16 + quad * 4 + r;
                float v = (acc[0][mtl][nt][r] + acc[1][mtl][nt][r] +
                           acc[2][mtl][nt][r]) * s;
                atomicAdd(&orow[pos * 32 + nt * 16 + m], v);
            }
}

extern "C" void kernel_launch(void* const* d_in, const int* in_sizes, int n_in,
                              void* d_out, int out_size, void* d_ws, size_t ws_size,
                              hipStream_t stream) {
    const float* x    = (const float*)d_in[0];
    const float* w1_0 = (const float*)d_in[1];
    const float* w1_1 = (const float*)d_in[2];
    const float* w2_0 = (const float*)d_in[3];
    const float* w2_1 = (const float*)d_in[4];
    float* out = (float*)d_out;

    u16* ws = (u16*)d_ws;
    u16* ws_x  = ws;                 // 193 cells (192 real + zero)
    u16* ws_w1 = ws + W1OFF;
    u16* ws_w2 = ws + W2OFF;
    u16* ws_h1 = ws + H1OFF;         // 3 x 193 cells x 7168

    prep<<<(PREP_TOT + 255) / 256, 256, 0, stream>>>(
        x, w1_0, w1_1, w2_0, w2_1, ws, out);
    conv1_k<<<192, 256, 0, stream>>>(ws_x, ws_w1, ws_h1);
    conv2_k<<<192, 256, 0, stream>>>(ws_h1, ws_w2, out);
}

// Round 5
// 121.332 us; speedup vs baseline: 1.4511x; 1.0270x over previous
//
#include <hip/hip_runtime.h>
#include <math.h>

// B=4, T=48, W=8, H=8, C=32; d_ff=64; periods {2,3,4}. T%P==0 always.
// (1x1 + 3^4)/2 inception folded into one 81-tap conv (center tap 40).
// R19: 9-phase restructure + small-block occupancy:
//   * Evidence R14/R15/R18: conv time ~ phases x ~1.1us regardless of
//     per-phase work (3x) and occupancy (3x); R15 (3 blk/CU) > R14 (2).
//     => cut phases 27->9 (one per (dl,dq) group, 9 taps in LDS chunk)
//     AND raise independent blocks/CU.
//   * Block = (per,bb,tp,half), 2 waves (wave = t-site), M=64 x N=32 per
//     wave (acc[4][2], wf reused across 4 af -> 1.33 MFMA/ds_read).
//   * LDS = 18 KB weight chunk + 14 KB acts = 32 KB exactly -> 5 blk/CU;
//     576 blocks ~2.25/CU co-resident; stalls hide across blocks (m114).
//   * Phase: stage(16 cp1k/wave) -> vmcnt(0) -> SBAR -> 72 MFMA -> SBAR.
//     Single-buffered, no WAR subtleties, 10 sync points/conv (was 28).
//   * Weights stay in LDS (R17's global->VGPR latency chain avoided).
//   * prep + all data layouts unchanged (verified in R15/R18).

typedef __attribute__((ext_vector_type(8))) short bf16x8;
typedef __attribute__((ext_vector_type(4))) float f32x4;
typedef unsigned short u16;

// ---- workspace offsets (u16 units) ----
#define XC 3200                 // u16 per x cell (10*10*32)
#define HC2 7168                // u16 per h1 cell (2 halves x 3584)
#define XSEG 617600             // 193 * XC   (cell 192 = zero cell)
#define ZSEG_END 639104         // + 3*7168 h1 zero-cell writes
#define W1OFF 639104            // 165888 bf16: [tap 0..80][nh(2)][1024]
#define W2OFF 804992            // 165888 bf16: [tap 0..80][kh(2)][1024]
#define H1OFF 970880            // 3 periods x 193 cells x 7168
#define H1P 1383424             // per-period stride = 193*7168
#define PREP_N 970880           // end of weight segment
#define OUT_Q 98304             // out-init float4 count (393216 fp32)
#define PREP_TOT (PREP_N + OUT_Q)

#define WAITVM(N) asm volatile("s_waitcnt vmcnt(" #N ")" ::: "memory")
#define SBAR()    asm volatile("s_barrier" ::: "memory")

__device__ __forceinline__ u16 f2bf(float f) {
    unsigned u = __float_as_uint(f);
    unsigned r = u + 0x7fffu + ((u >> 16) & 1u);
    return (u16)(r >> 16);
}
__device__ __forceinline__ float gelu_exact(float v) {
    return 0.5f * v * (1.0f + erff(v * 0.7071067811865476f));
}

// async copy of 1 KB: 64 lanes x 16 B. LDS dest = wave-uniform base + lane*16.
__device__ __forceinline__ void cp1k(const u16* g, u16* l, int lane) {
    __builtin_amdgcn_global_load_lds(
        (const __attribute__((address_space(1))) unsigned int*)(g + lane * 8),
        (__attribute__((address_space(3))) unsigned int*)(l + lane * 8),
        16, 0, 0);
}

// ---- prep: x cells (swizzled) + h1 zero cells + weights + out = x ----
__global__ __launch_bounds__(256) void prep(
    const float* __restrict__ x,
    const float* __restrict__ w1_0, const float* __restrict__ w1_1,
    const float* __restrict__ w2_0, const float* __restrict__ w2_1,
    u16* __restrict__ ws, float* __restrict__ out) {
    int i = blockIdx.x * 256 + threadIdx.x;
    if (i < XSEG) {
        int cellidx = i / XC; int inner = i - cellidx * XC;
        int cellpos = inner >> 5; int low = inner & 31;
        int sc = low >> 3, jj = low & 7;
        int c = ((sc ^ (cellpos & 3)) << 3) + jj;
        int wp = cellpos / 10, hp = cellpos - (cellpos / 10) * 10;
        float v = 0.f;
        if (cellidx < 192 && wp >= 1 && wp <= 8 && hp >= 1 && hp <= 8)
            v = x[(cellidx * 64 + (wp - 1) * 8 + (hp - 1)) * 32 + c];
        ws[i] = f2bf(v);
    } else if (i < ZSEG_END) {
        int j = i - XSEG;                 // 3 h1 zero cells (full 7168 each)
        int per = j / 7168; int off = j - per * 7168;
        ws[H1OFF + per * H1P + 192 * 7168 + off] = 0;
    } else if (i < W2OFF) {
        // w1: [tap][nh][chunkh(128)*8+jj], chunkh = (quad*2+nq)*16+m
        int j = i - W1OFF;
        int tap = j >> 11; int r = j & 2047;
        int nh = r >> 10; int rr = r & 1023;
        int chunkh = rr >> 3, jj = rr & 7;
        int m = chunkh & 15, nq = (chunkh >> 4) & 1, quad = chunkh >> 5;
        int o = nh * 32 + nq * 16 + m, c = quad * 8 + jj;
        float v = 0.5f * w1_1[(o * 32 + c) * 81 + tap];
        if (tap == 40) v += 0.5f * w1_0[o * 32 + c];
        ws[i] = f2bf(v);
    } else if (i < PREP_N) {
        // w2: [tap][kh][chunkh(128)*8+jj], chunkh = (quad*2+nt)*16+m
        int j = i - W2OFF;
        int tap = j >> 11; int r = j & 2047;
        int kh = r >> 10; int rr = r & 1023;
        int chunkh = rr >> 3, jj = rr & 7;
        int m = chunkh & 15, nt = (chunkh >> 4) & 1, quad = chunkh >> 5;
        int o = nt * 16 + m, c = kh * 32 + quad * 8 + jj;
        float v = 0.5f * w2_1[(o * 64 + c) * 81 + tap];
        if (tap == 40) v += 0.5f * w2_0[o * 64 + c];
        ws[i] = f2bf(v);
    } else if (i < PREP_TOT) {
        int j = i - PREP_N;
        ((float4*)out)[j] = ((const float4*)x)[j];
    }
}

// cell index for (b, l2, q2): valid -> b*48 + l2*P + q2, else zero cell 192
template<int P>
__device__ __forceinline__ int cidx(int bb, int l2, int q2) {
    constexpr int L = 48 / P;
    return ((unsigned)l2 < (unsigned)L && (unsigned)q2 < (unsigned)P)
               ? bb * 48 + l2 * P + q2 : 192;
}

// ---- conv1 (C32 -> 32 of C64, nh half) + GELU.
// Block = 2 waves (wave = t-site); wave tile M=64 pos x N=32 ch.
// 9 phases: {stage A(own cell)+W(9-tap chunk); vmcnt0; SBAR; 72 MFMA; SBAR}.
template<int P>
__device__ __forceinline__ void conv1_body(
    const u16* __restrict__ xs, const u16* __restrict__ w1b,
    u16* __restrict__ h1, int tp, int bb, int nh,
    u16* __restrict__ s_a, u16* __restrict__ s_w) {
    constexpr int HB = (P == 2) ? 0 : (P == 3) ? H1P : 2 * H1P;

    int tid = threadIdx.x;
    int lane = tid & 63, wv = tid >> 6;          // wv = t-site
    int m = lane & 15, quad = lane >> 4;
    int t0 = tp * 2, t = t0 + wv;
    int l = t / P, q = t - l * P;

    int sp[4];
#pragma unroll
    for (int mtl = 0; mtl < 4; ++mtl) {
        int pos = mtl * 16 + m;
        sp[mtl] = (pos >> 3) * 10 + (pos & 7);
    }

    f32x4 acc[4][2];
#pragma unroll
    for (int mtl = 0; mtl < 4; ++mtl)
#pragma unroll
        for (int nq = 0; nq < 2; ++nq) acc[mtl][nq] = f32x4{0.f, 0.f, 0.f, 0.f};

    const u16* ba = s_a + wv * 3584;             // own staged cell

#pragma unroll 1
    for (int g = 0; g < 9; ++g) {
        int dl = g / 3, dq = g - dl * 3;
        // stage own act cell: 7 pieces
        const u16* ac = xs + cidx<P>(bb, l + dl - 1, q + dq - 1) * XC;
        u16* ad = s_a + wv * 3584;
#pragma unroll
        for (int i = 0; i < 7; ++i)
            cp1k(ac + i * 512, ad + i * 512, lane);
        // stage 9-tap weight chunk (nh half): 18 pieces, 9/wave
#pragma unroll
        for (int i = 0; i < 9; ++i) {
            int k = wv * 9 + i;
            cp1k(w1b + (g * 9 + (k >> 1)) * 2048 + nh * 1024 + (k & 1) * 512,
                 s_w + k * 512, lane);
        }
        WAITVM(0); SBAR();                       // all 32 pieces delivered

#pragma unroll
        for (int pj = 0; pj < 9; ++pj) {
            int dw = pj / 3, dh = pj - (pj / 3) * 3;
            const u16* tw = s_w + pj * 1024;
            bf16x8 wf0 = *(const bf16x8*)(tw + (((quad * 2 + 0) * 16 + m) << 3));
            bf16x8 wf1 = *(const bf16x8*)(tw + (((quad * 2 + 1) * 16 + m) << 3));
#pragma unroll
            for (int mtl = 0; mtl < 4; ++mtl) {
                int cellpos = sp[mtl] + dw * 10 + dh;
                bf16x8 af = *(const bf16x8*)(ba + cellpos * 32 +
                                             ((quad ^ (cellpos & 3)) << 3));
                acc[mtl][0] = __builtin_amdgcn_mfma_f32_16x16x32_bf16(
                    af, wf0, acc[mtl][0], 0, 0, 0);
                acc[mtl][1] = __builtin_amdgcn_mfma_f32_16x16x32_bf16(
                    af, wf1, acc[mtl][1], 0, 0, 0);
            }
        }
        if (g < 8) SBAR();                       // WAR: readers done
    }

    // epilogue: GELU -> bf16 -> swizzled half-cell interior
    u16* hh = h1 + HB + (bb * 48 + t) * HC2 + nh * 3584;
#pragma unroll
    for (int mtl = 0; mtl < 4; ++mtl)
#pragma unroll
        for (int r = 0; r < 4; ++r) {
            int pos = mtl * 16 + quad * 4 + r;
            int cellpos = ((pos >> 3) + 1) * 10 + (pos & 7) + 1;
#pragma unroll
            for (int nq = 0; nq < 2; ++nq) {
                int ol = nq * 16 + m;
                hh[cellpos * 32 + (((ol >> 3) ^ (cellpos & 3)) << 3) + (ol & 7)] =
                    f2bf(gelu_exact(acc[mtl][nq][r]));
            }
        }
    // zero the 36 border cellpos of both t half-cells (unique writer)
#pragma unroll
    for (int it = 0; it < 9; ++it) {
        int k = it * 128 + tid;                  // 9*128 = 1152 exactly
        int tb = k >= 576; int rr = k - tb * 576;
        int bp = rr >> 4, u = rr & 15;
        int cp;
        if (bp < 10) cp = bp;
        else if (bp < 20) cp = 90 + (bp - 10);
        else if (bp < 28) cp = (bp - 19) * 10;
        else cp = (bp - 27) * 10 + 9;
        unsigned int* h32 = (unsigned int*)(h1 + HB +
            (bb * 48 + t0 + tb) * HC2 + nh * 3584);
        h32[cp * 16 + u] = 0;
    }
}

__global__ __launch_bounds__(128, 2) void conv1_k(
    const u16* __restrict__ ws_x, const u16* __restrict__ ws_w1,
    u16* __restrict__ ws_h1) {
    __shared__ __align__(16) u16 s_a[2 * 3584];  // 14 KB acts (1 cell/wave)
    __shared__ __align__(16) u16 s_w[18 * 512];  // 18 KB 9-tap chunk
    int g = blockIdx.x;
    int jid = (g & 7) * 72 + (g >> 3);           // XCD-chunked, 576 = 8*72
    int per = jid / 192; int rem = jid - per * 192;
    int bb = rem / 48; int r2 = rem - bb * 48;
    int tp = r2 >> 1, nh = r2 & 1;
    if (per == 0)      conv1_body<2>(ws_x, ws_w1, ws_h1, tp, bb, nh, s_a, s_w);
    else if (per == 1) conv1_body<3>(ws_x, ws_w1, ws_h1, tp, bb, nh, s_a, s_w);
    else               conv1_body<4>(ws_x, ws_w1, ws_h1, tp, bb, nh, s_a, s_w);
}

// ---- conv2 (32 of C64 -> C32 partial, kh half). Same 9-phase structure;
// epilogue atomicAdds acc/3 into out (pre-filled with x). ----
template<int P>
__device__ __forceinline__ void conv2_body(
    const u16* __restrict__ h1, const u16* __restrict__ w2b,
    float* __restrict__ out, int tp, int bb, int kh,
    u16* __restrict__ s_a, u16* __restrict__ s_w) {
    constexpr int HB = (P == 2) ? 0 : (P == 3) ? H1P : 2 * H1P;

    int tid = threadIdx.x;
    int lane = tid & 63, wv = tid >> 6;
    int m = lane & 15, quad = lane >> 4;
    int t0 = tp * 2, t = t0 + wv;
    int l = t / P, q = t - l * P;
    const u16* hb = h1 + HB;

    int sp[4];
#pragma unroll
    for (int mtl = 0; mtl < 4; ++mtl) {
        int pos = mtl * 16 + m;
        sp[mtl] = (pos >> 3) * 10 + (pos & 7);
    }

    f32x4 acc[4][2];
#pragma unroll
    for (int mtl = 0; mtl < 4; ++mtl)
#pragma unroll
        for (int nt = 0; nt < 2; ++nt) acc[mtl][nt] = f32x4{0.f, 0.f, 0.f, 0.f};

    const u16* ba = s_a + wv * 3584;

#pragma unroll 1
    for (int g = 0; g < 9; ++g) {
        int dl = g / 3, dq = g - dl * 3;
        const u16* ac = hb + cidx<P>(bb, l + dl - 1, q + dq - 1) * HC2 +
                        kh * 3584;
        u16* ad = s_a + wv * 3584;
#pragma unroll
        for (int i = 0; i < 7; ++i)
            cp1k(ac + i * 512, ad + i * 512, lane);
#pragma unroll
        for (int i = 0; i < 9; ++i) {
            int k = wv * 9 + i;
            cp1k(w2b + (g * 9 + (k >> 1)) * 2048 + kh * 1024 + (k & 1) * 512,
                 s_w + k * 512, lane);
        }
        WAITVM(0); SBAR();

#pragma unroll
        for (int pj = 0; pj < 9; ++pj) {
            int dw = pj / 3, dh = pj - (pj / 3) * 3;
            const u16* tw = s_w + pj * 1024;
            bf16x8 wf0 = *(const bf16x8*)(tw + (((quad * 2 + 0) * 16 + m) << 3));
            bf16x8 wf1 = *(const bf16x8*)(tw + (((quad * 2 + 1) * 16 + m) << 3));
#pragma unroll
            for (int mtl = 0; mtl < 4; ++mtl) {
                int cellpos = sp[mtl] + dw * 10 + dh;
                bf16x8 af = *(const bf16x8*)(ba + cellpos * 32 +
                                             ((quad ^ (cellpos & 3)) << 3));
                acc[mtl][0] = __builtin_amdgcn_mfma_f32_16x16x32_bf16(
                    af, wf0, acc[mtl][0], 0, 0, 0);
                acc[mtl][1] = __builtin_amdgcn_mfma_f32_16x16x32_bf16(
                    af, wf1, acc[mtl][1], 0, 0, 0);
            }
        }
        if (g < 8) SBAR();
    }

    // epilogue: out += (acc)/3 ; out pre-filled with x
    float* orow = out + (bb * 48 + t) * 2048;
    const float s = 1.0f / 3.0f;
#pragma unroll
    for (int mtl = 0; mtl < 4; ++mtl)
#pragma unroll
        for (int nt = 0; nt < 2; ++nt)
#pragma unroll
            for (int r = 0; r < 4; ++r) {
                int pos = mtl * 16 + quad * 4 + r;
                atomicAdd(&orow[pos * 32 + nt * 16 + m], acc[mtl][nt][r] * s);
            }
}

__global__ __launch_bounds__(128, 2) void conv2_k(
    const u16* __restrict__ ws_h1, const u16* __restrict__ ws_w2,
    float* __restrict__ out) {
    __shared__ __align__(16) u16 s_a[2 * 3584];  // 14 KB
    __shared__ __align__(16) u16 s_w[18 * 512];  // 18 KB
    int g = blockIdx.x;
    int jid = (g & 7) * 72 + (g >> 3);           // same XCD mapping as conv1
    int per = jid / 192; int rem = jid - per * 192;
    int bb = rem / 48; int r2 = rem - bb * 48;
    int tp = r2 >> 1, kh = r2 & 1;
    if (per == 0)      conv2_body<2>(ws_h1, ws_w2, out, tp, bb, kh, s_a, s_w);
    else if (per == 1) conv2_body<3>(ws_h1, ws_w2, out, tp, bb, kh, s_a, s_w);
    else               conv2_body<4>(ws_h1, ws_w2, out, tp, bb, kh, s_a, s_w);
}

extern "C" void kernel_launch(void* const* d_in, const int* in_sizes, int n_in,
                              void* d_out, int out_size, void* d_ws, size_t ws_size,
                              hipStream_t stream) {
    const float* x    = (const float*)d_in[0];
    const float* w1_0 = (const float*)d_in[1];
    const float* w1_1 = (const float*)d_in[2];
    const float* w2_0 = (const float*)d_in[3];
    const float* w2_1 = (const float*)d_in[4];
    float* out = (float*)d_out;

    u16* ws = (u16*)d_ws;
    u16* ws_x  = ws;                 // 193 cells (192 real + zero)
    u16* ws_w1 = ws + W1OFF;
    u16* ws_w2 = ws + W2OFF;
    u16* ws_h1 = ws + H1OFF;         // 3 x 193 cells x 7168

    prep<<<(PREP_TOT + 255) / 256, 256, 0, stream>>>(
        x, w1_0, w1_1, w2_0, w2_1, ws, out);
    conv1_k<<<576, 128, 0, stream>>>(ws_x, ws_w1, ws_h1);
    conv2_k<<<576, 128, 0, stream>>>(ws_h1, ws_w2, out);
}

// Round 6
// 118.871 us; speedup vs baseline: 1.4812x; 1.0207x over previous
//
#include <hip/hip_runtime.h>
#include <math.h>

// B=4, T=48, W=8, H=8, C=32; d_ff=64; periods {2,3,4}. T%P==0 always.
// (1x1 + 3^4)/2 inception folded into one 81-tap conv (center tap 40).
// R20: t-sextet fusion + static act window + weight-only main loop.
//   Model from R14-R19: conv_time ~ max(staged_bytes/~6TB/s,
//   phases x exposed_latency(occupancy)). Attack both:
//   * block = (per,bb,tpp(6 t-sites),half) = 192 blocks x 12 waves (768thr).
//     wave = (ts in 6, mh in 2): M=32 pos x N=32 ch, acc[2][2].
//   * acts: neighbor cell of site t for (dl,dq) is t + (dl-1)P + (dq-1) ->
//     static window of <=16 cells + zero slot staged ONCE in prologue
//     (119 KB LDS). No act staging in main loop, no WAR hazards.
//   * main loop: weight ring only (mod-4, depth-2): waves 0-5 issue 1 KB
//     each per phase, prefetched 2 phases ahead -> WAITVM(2) pre-satisfied.
//     Ladder traced: steady 2, tail 1, 0. Non-staging waves' vmcnt==0 so
//     the same WAITVM is a no-op for them (vmcnt is per-wave).
//   * staged bytes both convs: 330 MB (R15) -> 108 MB; 12 waves/CU
//     (vs R18's 4 which exposed latency).
//   * conv2 atomics unchanged from R15 (2.36M, 6 partials/output + x-init).

typedef __attribute__((ext_vector_type(8))) short bf16x8;
typedef __attribute__((ext_vector_type(4))) float f32x4;
typedef unsigned short u16;

// ---- workspace offsets (u16 units) ----
#define XC 3200                 // u16 per x cell (10*10*32)
#define HC2 7168                // u16 per h1 cell (2 halves x 3584)
#define XSEG 617600             // 193 * XC   (cell 192 = zero cell)
#define ZSEG_END 639104         // + 3*7168 h1 zero-cell writes
#define W1OFF 639104            // 165888 bf16: [tap 0..80][nh(2)][1024]
#define W2OFF 804992            // 165888 bf16: [tap 0..80][kh(2)][1024]
#define H1OFF 970880            // 3 periods x 193 cells x 7168
#define H1P 1383424             // per-period stride = 193*7168
#define PREP_N 970880           // end of weight segment
#define OUT_Q 98304             // out-init float4 count (393216 fp32)
#define PREP_TOT (PREP_N + OUT_Q)

#define WAITVM(N) asm volatile("s_waitcnt vmcnt(" #N ")" ::: "memory")
#define SBAR()    asm volatile("s_barrier" ::: "memory")

__device__ __forceinline__ u16 f2bf(float f) {
    unsigned u = __float_as_uint(f);
    unsigned r = u + 0x7fffu + ((u >> 16) & 1u);
    return (u16)(r >> 16);
}
__device__ __forceinline__ float gelu_exact(float v) {
    return 0.5f * v * (1.0f + erff(v * 0.7071067811865476f));
}

// async copy of 1 KB: 64 lanes x 16 B. LDS dest = wave-uniform base + lane*16.
__device__ __forceinline__ void cp1k(const u16* g, u16* l, int lane) {
    __builtin_amdgcn_global_load_lds(
        (const __attribute__((address_space(1))) unsigned int*)(g + lane * 8),
        (__attribute__((address_space(3))) unsigned int*)(l + lane * 8),
        16, 0, 0);
}

// ---- prep: x cells (swizzled) + h1 zero cells + weights + out = x ----
__global__ __launch_bounds__(256) void prep(
    const float* __restrict__ x,
    const float* __restrict__ w1_0, const float* __restrict__ w1_1,
    const float* __restrict__ w2_0, const float* __restrict__ w2_1,
    u16* __restrict__ ws, float* __restrict__ out) {
    int i = blockIdx.x * 256 + threadIdx.x;
    if (i < XSEG) {
        int cellidx = i / XC; int inner = i - cellidx * XC;
        int cellpos = inner >> 5; int low = inner & 31;
        int sc = low >> 3, jj = low & 7;
        int c = ((sc ^ (cellpos & 3)) << 3) + jj;
        int wp = cellpos / 10, hp = cellpos - (cellpos / 10) * 10;
        float v = 0.f;
        if (cellidx < 192 && wp >= 1 && wp <= 8 && hp >= 1 && hp <= 8)
            v = x[(cellidx * 64 + (wp - 1) * 8 + (hp - 1)) * 32 + c];
        ws[i] = f2bf(v);
    } else if (i < ZSEG_END) {
        int j = i - XSEG;                 // 3 h1 zero cells (full 7168 each)
        int per = j / 7168; int off = j - per * 7168;
        ws[H1OFF + per * H1P + 192 * 7168 + off] = 0;
    } else if (i < W2OFF) {
        // w1: [tap][nh][chunkh(128)*8+jj], chunkh = (quad*2+nq)*16+m
        int j = i - W1OFF;
        int tap = j >> 11; int r = j & 2047;
        int nh = r >> 10; int rr = r & 1023;
        int chunkh = rr >> 3, jj = rr & 7;
        int m = chunkh & 15, nq = (chunkh >> 4) & 1, quad = chunkh >> 5;
        int o = nh * 32 + nq * 16 + m, c = quad * 8 + jj;
        float v = 0.5f * w1_1[(o * 32 + c) * 81 + tap];
        if (tap == 40) v += 0.5f * w1_0[o * 32 + c];
        ws[i] = f2bf(v);
    } else if (i < PREP_N) {
        // w2: [tap][kh][chunkh(128)*8+jj], chunkh = (quad*2+nt)*16+m
        int j = i - W2OFF;
        int tap = j >> 11; int r = j & 2047;
        int kh = r >> 10; int rr = r & 1023;
        int chunkh = rr >> 3, jj = rr & 7;
        int m = chunkh & 15, nt = (chunkh >> 4) & 1, quad = chunkh >> 5;
        int o = nt * 16 + m, c = kh * 32 + quad * 8 + jj;
        float v = 0.5f * w2_1[(o * 64 + c) * 81 + tap];
        if (tap == 40) v += 0.5f * w2_0[o * 64 + c];
        ws[i] = f2bf(v);
    } else if (i < PREP_TOT) {
        int j = i - PREP_N;
        ((float4*)out)[j] = ((const float4*)x)[j];
    }
}

// ---- conv1 (C32 -> 32 of C64, nh half), 6 t-sites per block + GELU.
// 12 waves = (ts in 6, mh in 2). Static act window; weight ring main loop.
template<int P>
__device__ __forceinline__ void conv1_body(
    const u16* __restrict__ xs, const u16* __restrict__ w1b,
    u16* __restrict__ h1, int tpp, int bb, int nh,
    u16* __restrict__ s_a, u16* __restrict__ s_w) {
    constexpr int HB = (P == 2) ? 0 : (P == 3) ? H1P : 2 * H1P;
    constexpr int L = 48 / P;
    constexpr int EXT = P + 1;
    constexpr int NW = 6 + 2 * EXT;      // window cells (12/14/16)
    constexpr int ZS = NW;               // zero slot index
    constexpr int NP = (NW + 1) * 7;     // staged pieces

    int tid = threadIdx.x;
    int lane = tid & 63, wv = tid >> 6;  // 12 waves
    int m = lane & 15, quad = lane >> 4;
    int ts = wv >> 1, mh = wv & 1;
    int t0 = tpp * 6, t = t0 + ts;
    int l = t / P, q = t - l * P;

    int sp[2];
#pragma unroll
    for (int mtl = 0; mtl < 2; ++mtl) {
        int pos = (mh * 2 + mtl) * 16 + m;
        sp[mtl] = (pos >> 3) * 10 + (pos & 7);
    }

    f32x4 acc[2][2];
#pragma unroll
    for (int mtl = 0; mtl < 2; ++mtl)
#pragma unroll
        for (int nq = 0; nq < 2; ++nq) acc[mtl][nq] = f32x4{0.f, 0.f, 0.f, 0.f};

    // prologue: stage act window once (slot si <-> t' = t0-EXT+si; ZS = zero)
    for (int p = wv; p < NP; p += 12) {
        int si = p / 7, pc = p - si * 7;
        int tt = t0 - EXT + si;
        int cell = (si == ZS) ? 192
                 : (((unsigned)tt < 48u) ? bb * 48 + tt : 192);
        cp1k(xs + cell * XC + pc * 512, s_a + si * 3584 + pc * 512, lane);
    }
    // W(0), W(1): waves 0-5 carry 1 piece each per chunk (tap wv>>1, part wv&1)
    if (wv < 6) {
        cp1k(w1b + (0 * 3 + (wv >> 1)) * 2048 + nh * 1024 + (wv & 1) * 512,
             s_w + 0 * 3072 + wv * 512, lane);
        cp1k(w1b + (1 * 3 + (wv >> 1)) * 2048 + nh * 1024 + (wv & 1) * 512,
             s_w + 1 * 3072 + wv * 512, lane);
        WAITVM(1);                       // acts + W0 done, W1 in flight
    } else {
        WAITVM(0);                       // acts done
    }
    SBAR();

#pragma unroll 1
    for (int cg = 0; cg < 27; ++cg) {
        // issue W(cg+2) into slot (cg+2)&3 (last read at cg-2, fenced by
        // SBAR@cg-1). Writer's own WAITVM(2)@cg+2 + SBAR publishes delivery.
        if (wv < 6 && cg < 25)
            cp1k(w1b + ((cg + 2) * 3 + (wv >> 1)) * 2048 + nh * 1024 +
                     (wv & 1) * 512,
                 s_w + ((cg + 2) & 3) * 3072 + wv * 512, lane);
        // per-wave queue (wv<6): [W(cg),W(cg+1),W(cg+2)] -> 2; tail 1, 0.
        if (cg < 25)       { WAITVM(2); }
        else if (cg == 25) { WAITVM(1); }
        else               { WAITVM(0); }
        SBAR();

        int g2 = cg / 3, dw = cg - g2 * 3;
        int dl = g2 / 3, dq = g2 - dl * 3;
        int lq = l + dl - 1, qq = q + dq - 1;
        bool valid = ((unsigned)lq < (unsigned)L) &&
                     ((unsigned)qq < (unsigned)P);
        int si = valid ? (ts + dl * P + dq) : ZS;   // t'-(t0-EXT), in [0,NW)
        const u16* ba = s_a + si * 3584;
        const u16* bw = s_w + (cg & 3) * 3072;
#pragma unroll
        for (int j = 0; j < 3; ++j) {
            const u16* tw = bw + j * 1024;
            bf16x8 wf0 = *(const bf16x8*)(tw + (((quad * 2 + 0) * 16 + m) << 3));
            bf16x8 wf1 = *(const bf16x8*)(tw + (((quad * 2 + 1) * 16 + m) << 3));
#pragma unroll
            for (int mtl = 0; mtl < 2; ++mtl) {
                int cellpos = sp[mtl] + dw * 10 + j;
                bf16x8 af = *(const bf16x8*)(ba + cellpos * 32 +
                                             ((quad ^ (cellpos & 3)) << 3));
                acc[mtl][0] = __builtin_amdgcn_mfma_f32_16x16x32_bf16(
                    af, wf0, acc[mtl][0], 0, 0, 0);
                acc[mtl][1] = __builtin_amdgcn_mfma_f32_16x16x32_bf16(
                    af, wf1, acc[mtl][1], 0, 0, 0);
            }
        }
    }

    // epilogue: GELU -> bf16 -> swizzled half-cell interior
    u16* hh = h1 + HB + (bb * 48 + t) * HC2 + nh * 3584;
#pragma unroll
    for (int mtl = 0; mtl < 2; ++mtl)
#pragma unroll
        for (int r = 0; r < 4; ++r) {
            int pos = (mh * 2 + mtl) * 16 + quad * 4 + r;
            int cellpos = ((pos >> 3) + 1) * 10 + (pos & 7) + 1;
#pragma unroll
            for (int nq = 0; nq < 2; ++nq) {
                int ol = nq * 16 + m;
                hh[cellpos * 32 + (((ol >> 3) ^ (cellpos & 3)) << 3) + (ol & 7)] =
                    f2bf(gelu_exact(acc[mtl][nq][r]));
            }
        }
    // zero the 36 border cellpos of all 6 t half-cells (unique writer)
#pragma unroll
    for (int it = 0; it < 5; ++it) {
        int k = it * 768 + tid;                    // 6*576 = 3456 entries
        if (k < 3456) {
            int tc = k / 576; int rr = k - tc * 576;
            int bp = rr >> 4, u = rr & 15;
            int cp;
            if (bp < 10) cp = bp;
            else if (bp < 20) cp = 90 + (bp - 10);
            else if (bp < 28) cp = (bp - 19) * 10;
            else cp = (bp - 27) * 10 + 9;
            unsigned int* h32 = (unsigned int*)(h1 + HB +
                (bb * 48 + t0 + tc) * HC2 + nh * 3584);
            h32[cp * 16 + u] = 0;
        }
    }
}

__global__ __launch_bounds__(768) void conv1_k(
    const u16* __restrict__ ws_x, const u16* __restrict__ ws_w1,
    u16* __restrict__ ws_h1) {
    __shared__ __align__(16) u16 s_a[17 * 3584];   // 119 KB act window
    __shared__ __align__(16) u16 s_w[4 * 3072];    // 24 KB weight ring
    int g = blockIdx.x;
    int jid = (g & 7) * 24 + (g >> 3);             // XCD-chunked, 192 = 8*24
    int per = jid / 64; int rem = jid - per * 64;
    int bb = rem / 16; int r2 = rem - bb * 16;
    int tpp = r2 >> 1, nh = r2 & 1;
    if (per == 0)      conv1_body<2>(ws_x, ws_w1, ws_h1, tpp, bb, nh, s_a, s_w);
    else if (per == 1) conv1_body<3>(ws_x, ws_w1, ws_h1, tpp, bb, nh, s_a, s_w);
    else               conv1_body<4>(ws_x, ws_w1, ws_h1, tpp, bb, nh, s_a, s_w);
}

// ---- conv2 (32 of C64 -> C32 partial, kh half), 6 t-sites per block.
// Same structure; epilogue atomicAdds acc/3 into out (pre-filled with x). ----
template<int P>
__device__ __forceinline__ void conv2_body(
    const u16* __restrict__ h1, const u16* __restrict__ w2b,
    float* __restrict__ out, int tpp, int bb, int kh,
    u16* __restrict__ s_a, u16* __restrict__ s_w) {
    constexpr int HB = (P == 2) ? 0 : (P == 3) ? H1P : 2 * H1P;
    constexpr int L = 48 / P;
    constexpr int EXT = P + 1;
    constexpr int NW = 6 + 2 * EXT;
    constexpr int ZS = NW;
    constexpr int NP = (NW + 1) * 7;

    int tid = threadIdx.x;
    int lane = tid & 63, wv = tid >> 6;
    int m = lane & 15, quad = lane >> 4;
    int ts = wv >> 1, mh = wv & 1;
    int t0 = tpp * 6, t = t0 + ts;
    int l = t / P, q = t - l * P;
    const u16* hb = h1 + HB;

    int sp[2];
#pragma unroll
    for (int mtl = 0; mtl < 2; ++mtl) {
        int pos = (mh * 2 + mtl) * 16 + m;
        sp[mtl] = (pos >> 3) * 10 + (pos & 7);
    }

    f32x4 acc[2][2];
#pragma unroll
    for (int mtl = 0; mtl < 2; ++mtl)
#pragma unroll
        for (int nt = 0; nt < 2; ++nt) acc[mtl][nt] = f32x4{0.f, 0.f, 0.f, 0.f};

    for (int p = wv; p < NP; p += 12) {
        int si = p / 7, pc = p - si * 7;
        int tt = t0 - EXT + si;
        int cell = (si == ZS) ? 192
                 : (((unsigned)tt < 48u) ? bb * 48 + tt : 192);
        cp1k(hb + cell * HC2 + kh * 3584 + pc * 512,
             s_a + si * 3584 + pc * 512, lane);
    }
    if (wv < 6) {
        cp1k(w2b + (0 * 3 + (wv >> 1)) * 2048 + kh * 1024 + (wv & 1) * 512,
             s_w + 0 * 3072 + wv * 512, lane);
        cp1k(w2b + (1 * 3 + (wv >> 1)) * 2048 + kh * 1024 + (wv & 1) * 512,
             s_w + 1 * 3072 + wv * 512, lane);
        WAITVM(1);
    } else {
        WAITVM(0);
    }
    SBAR();

#pragma unroll 1
    for (int cg = 0; cg < 27; ++cg) {
        if (wv < 6 && cg < 25)
            cp1k(w2b + ((cg + 2) * 3 + (wv >> 1)) * 2048 + kh * 1024 +
                     (wv & 1) * 512,
                 s_w + ((cg + 2) & 3) * 3072 + wv * 512, lane);
        if (cg < 25)       { WAITVM(2); }
        else if (cg == 25) { WAITVM(1); }
        else               { WAITVM(0); }
        SBAR();

        int g2 = cg / 3, dw = cg - g2 * 3;
        int dl = g2 / 3, dq = g2 - dl * 3;
        int lq = l + dl - 1, qq = q + dq - 1;
        bool valid = ((unsigned)lq < (unsigned)L) &&
                     ((unsigned)qq < (unsigned)P);
        int si = valid ? (ts + dl * P + dq) : ZS;
        const u16* ba = s_a + si * 3584;
        const u16* bw = s_w + (cg & 3) * 3072;
#pragma unroll
        for (int j = 0; j < 3; ++j) {
            const u16* tw = bw + j * 1024;
            bf16x8 wf0 = *(const bf16x8*)(tw + (((quad * 2 + 0) * 16 + m) << 3));
            bf16x8 wf1 = *(const bf16x8*)(tw + (((quad * 2 + 1) * 16 + m) << 3));
#pragma unroll
            for (int mtl = 0; mtl < 2; ++mtl) {
                int cellpos = sp[mtl] + dw * 10 + j;
                bf16x8 af = *(const bf16x8*)(ba + cellpos * 32 +
                                             ((quad ^ (cellpos & 3)) << 3));
                acc[mtl][0] = __builtin_amdgcn_mfma_f32_16x16x32_bf16(
                    af, wf0, acc[mtl][0], 0, 0, 0);
                acc[mtl][1] = __builtin_amdgcn_mfma_f32_16x16x32_bf16(
                    af, wf1, acc[mtl][1], 0, 0, 0);
            }
        }
    }

    // epilogue: out += acc/3 (softmax(ones) weights); out pre-filled with x
    float* orow = out + (bb * 48 + t) * 2048;
    const float s = 1.0f / 3.0f;
#pragma unroll
    for (int mtl = 0; mtl < 2; ++mtl)
#pragma unroll
        for (int nt = 0; nt < 2; ++nt)
#pragma unroll
            for (int r = 0; r < 4; ++r) {
                int pos = (mh * 2 + mtl) * 16 + quad * 4 + r;
                atomicAdd(&orow[pos * 32 + nt * 16 + m], acc[mtl][nt][r] * s);
            }
}

__global__ __launch_bounds__(768) void conv2_k(
    const u16* __restrict__ ws_h1, const u16* __restrict__ ws_w2,
    float* __restrict__ out) {
    __shared__ __align__(16) u16 s_a[17 * 3584];   // 119 KB act window
    __shared__ __align__(16) u16 s_w[4 * 3072];    // 24 KB weight ring
    int g = blockIdx.x;
    int jid = (g & 7) * 24 + (g >> 3);             // same XCD mapping as conv1
    int per = jid / 64; int rem = jid - per * 64;
    int bb = rem / 16; int r2 = rem - bb * 16;
    int tpp = r2 >> 1, kh = r2 & 1;
    if (per == 0)      conv2_body<2>(ws_h1, ws_w2, out, tpp, bb, kh, s_a, s_w);
    else if (per == 1) conv2_body<3>(ws_h1, ws_w2, out, tpp, bb, kh, s_a, s_w);
    else               conv2_body<4>(ws_h1, ws_w2, out, tpp, bb, kh, s_a, s_w);
}

extern "C" void kernel_launch(void* const* d_in, const int* in_sizes, int n_in,
                              void* d_out, int out_size, void* d_ws, size_t ws_size,
                              hipStream_t stream) {
    const float* x    = (const float*)d_in[0];
    const float* w1_0 = (const float*)d_in[1];
    const float* w1_1 = (const float*)d_in[2];
    const float* w2_0 = (const float*)d_in[3];
    const float* w2_1 = (const float*)d_in[4];
    float* out = (float*)d_out;

    u16* ws = (u16*)d_ws;
    u16* ws_x  = ws;                 // 193 cells (192 real + zero)
    u16* ws_w1 = ws + W1OFF;
    u16* ws_w2 = ws + W2OFF;
    u16* ws_h1 = ws + H1OFF;         // 3 x 193 cells x 7168

    prep<<<(PREP_TOT + 255) / 256, 256, 0, stream>>>(
        x, w1_0, w1_1, w2_0, w2_1, ws, out);
    conv1_k<<<192, 768, 0, stream>>>(ws_x, ws_w1, ws_h1);
    conv2_k<<<192, 768, 0, stream>>>(ws_h1, ws_w2, out);
}